// Round 1
// baseline (661.180 us; speedup 1.0000x reference)
//
#include <hip/hip_runtime.h>
#include <hip/hip_bf16.h>
#include <math.h>

// Problem constants
#define Bsz   256
#define INDIM 2048
#define Dd    128
#define Kq    65536
#define NH    32
#define S1n   16
#define S2n   16
#define ROWLEN (1 + Kq + S1n + S2n)   // 65569
#define CAP   2048
#define NCHUNK 4                       // split-K chunks of 512 for encoder GEMM

// ---------------- Kernel A1: fp64 split-K encoder GEMM ----------------
// virtual rows 0..255 = q @ W_q ; 256..511 = k @ (0.999*W_k + (1-0.999)*W_q)
// grid: (NCHUNK, 64), block 256. Each block: 8 rows x 128 cols x 512 k-chunk.
__global__ __launch_bounds__(256) void moco_a1(const float* __restrict__ q,
                                               const float* __restrict__ k,
                                               const float* __restrict__ Wq,
                                               const float* __restrict__ Wk,
                                               double* __restrict__ part) {
    int kc   = blockIdx.x;        // 0..3
    int grp  = blockIdx.y;        // 0..63
    int vrow0 = grp * 8;
    bool isK = (vrow0 >= Bsz);
    const float* inp = isK ? k : q;
    int row0 = isK ? (vrow0 - Bsz) : vrow0;
    int i0 = kc * 512;

    __shared__ float s_in[8 * 512];
    for (int idx = threadIdx.x; idx < 8 * 512; idx += 256) {
        int rr = idx >> 9, ii = idx & 511;
        s_in[idx] = inp[(size_t)(row0 + rr) * INDIM + i0 + ii];
    }
    __syncthreads();

    int d  = threadIdx.x & 127;
    int rg = threadIdx.x >> 7;    // 0/1 -> rows rg*4 .. rg*4+3
    double acc0 = 0, acc1 = 0, acc2 = 0, acc3 = 0;
    const double M = 0.999, OM = 1.0 - 0.999;

    #pragma unroll 4
    for (int i = 0; i < 512; ++i) {
        int gi = i0 + i;
        double w;
        float wq = Wq[(size_t)gi * Dd + d];
        if (isK) {
            float wk = Wk[(size_t)gi * Dd + d];
            w = M * (double)wk + OM * (double)wq;
        } else {
            w = (double)wq;
        }
        const float* sr = &s_in[(rg * 4) * 512 + i];
        acc0 += (double)sr[0]    * w;
        acc1 += (double)sr[512]  * w;
        acc2 += (double)sr[1024] * w;
        acc3 += (double)sr[1536] * w;
    }
    double* pout = part + (((size_t)kc * 512) + vrow0 + rg * 4) * Dd + d;
    pout[0]       = acc0;
    pout[Dd]      = acc1;
    pout[2 * Dd]  = acc2;
    pout[3 * Dd]  = acc3;
}

// ---------------- Kernel A2: combine chunks, normalize (f64), pos logit, labels ----
// grid: 256 (one per b), block 128 (one per d)
__global__ __launch_bounds__(128) void moco_a2(const double* __restrict__ part,
                                               double* __restrict__ outq64,
                                               float* __restrict__ outq32,
                                               float* __restrict__ out) {
    int b = blockIdx.x, d = threadIdx.x;
    double sq = 0, sk = 0;
    #pragma unroll
    for (int kc = 0; kc < NCHUNK; ++kc) {
        sq += part[(((size_t)kc * 512) + b) * Dd + d];
        sk += part[(((size_t)kc * 512) + Bsz + b) * Dd + d];
    }
    __shared__ double red[128];
    red[d] = sq * sq; __syncthreads();
    for (int s = 64; s > 0; s >>= 1) { if (d < s) red[d] += red[d + s]; __syncthreads(); }
    double nq = sqrt(red[0]); __syncthreads();
    red[d] = sk * sk; __syncthreads();
    for (int s = 64; s > 0; s >>= 1) { if (d < s) red[d] += red[d + s]; __syncthreads(); }
    double nk = sqrt(red[0]); __syncthreads();

    double oq = sq / fmax(nq, 1e-12);
    double ok = sk / fmax(nk, 1e-12);
    outq64[(size_t)b * Dd + d] = oq;
    outq32[(size_t)b * Dd + d] = (float)oq;

    red[d] = oq * ok; __syncthreads();
    for (int s = 64; s > 0; s >>= 1) { if (d < s) red[d] += red[d + s]; __syncthreads(); }
    if (d == 0) {
        out[(size_t)b * ROWLEN] = (float)(red[0] / 0.07);
        ((int*)out)[(size_t)Bsz * ROWLEN + b] = 0;   // labels
    }
}

// ---------------- Kernel B: fp32 GEMM out_q @ queue^T / T -> out[:,1:1+K] ----------
#define BM 128
#define BN 64
#define BK 64
__global__ __launch_bounds__(256) void moco_gemmB(const float* __restrict__ A,
                                                  const float* __restrict__ Q,
                                                  float* __restrict__ out) {
    int bn0 = blockIdx.x * BN;
    int bm0 = blockIdx.y * BM;
    __shared__ float a_s[BK][BM + 1];
    __shared__ float b_s[BK][BN + 1];
    int tx = threadIdx.x & 15;   // col group
    int ty = threadIdx.x >> 4;   // row group
    float acc[8][4] = {};

    for (int k0 = 0; k0 < Dd; k0 += BK) {
        for (int idx = threadIdx.x; idx < BM * BK; idx += 256) {
            int kk = idx & (BK - 1), m = idx >> 6;
            a_s[kk][m] = A[(size_t)(bm0 + m) * Dd + k0 + kk];
        }
        for (int idx = threadIdx.x; idx < BN * BK; idx += 256) {
            int kk = idx & (BK - 1), n = idx >> 6;
            b_s[kk][n] = Q[(size_t)(bn0 + n) * Dd + k0 + kk];
        }
        __syncthreads();
        #pragma unroll 8
        for (int kk = 0; kk < BK; ++kk) {
            float ar[8], br[4];
            #pragma unroll
            for (int i = 0; i < 8; ++i) ar[i] = a_s[kk][ty + 16 * i];
            #pragma unroll
            for (int j = 0; j < 4; ++j) br[j] = b_s[kk][tx + 16 * j];
            #pragma unroll
            for (int i = 0; i < 8; ++i)
                #pragma unroll
                for (int j = 0; j < 4; ++j)
                    acc[i][j] += ar[i] * br[j];
        }
        __syncthreads();
    }
    const float invT = (float)(1.0 / 0.07);
    #pragma unroll
    for (int i = 0; i < 8; ++i) {
        size_t rowoff = (size_t)(bm0 + ty + 16 * i) * ROWLEN + 1 + bn0;
        #pragma unroll
        for (int j = 0; j < 4; ++j)
            out[rowoff + tx + 16 * j] = acc[i][j] * invT;
    }
}

// ---------------- Kernel C: per-row top-candidate selection (histogram) ----------
__global__ __launch_bounds__(256) void moco_topcand(const float* __restrict__ out,
                                                    int* __restrict__ cand,
                                                    int* __restrict__ ccnt) {
    int row = blockIdx.x;
    const float* p = out + (size_t)row * ROWLEN + 1;
    __shared__ unsigned hist[4096];
    __shared__ int s_bstar;
    __shared__ int s_cnt;
    for (int i = threadIdx.x; i < 4096; i += 256) hist[i] = 0;
    if (threadIdx.x == 0) s_cnt = 0;
    __syncthreads();

    for (int c = threadIdx.x; c < Kq; c += 256) {
        unsigned u = __float_as_uint(p[c]);
        u = (u & 0x80000000u) ? ~u : (u | 0x80000000u);
        atomicAdd(&hist[u >> 20], 1u);
    }
    __syncthreads();
    if (threadIdx.x == 0) {
        unsigned cum = 0;
        int bin = 4095;
        for (; bin > 0; --bin) { cum += hist[bin]; if (cum >= NH) break; }
        s_bstar = (bin > 0) ? (bin - 1) : 0;   // one extra bin of safety margin
    }
    __syncthreads();
    unsigned bstar = (unsigned)s_bstar;
    for (int c = threadIdx.x; c < Kq; c += 256) {
        unsigned u = __float_as_uint(p[c]);
        u = (u & 0x80000000u) ? ~u : (u | 0x80000000u);
        if ((u >> 20) >= bstar) {
            int pos = atomicAdd(&s_cnt, 1);
            if (pos < CAP) cand[(size_t)row * CAP + pos] = c;
        }
    }
    __syncthreads();
    if (threadIdx.x == 0) ccnt[row] = (s_cnt < CAP) ? s_cnt : CAP;
}

// ---------------- Kernel D: fp64 re-rank + mixed-negative logits ----------------
__global__ __launch_bounds__(256) void moco_finalize(const double* __restrict__ outq64,
                                                     const float* __restrict__ Qm,
                                                     const int* __restrict__ cand,
                                                     const int* __restrict__ ccnt,
                                                     const float* __restrict__ alpha,
                                                     const float* __restrict__ beta,
                                                     const int* __restrict__ i1a,
                                                     const int* __restrict__ i1b,
                                                     const int* __restrict__ i2,
                                                     float* __restrict__ out) {
    int row = blockIdx.x;
    __shared__ double oq[Dd];
    __shared__ double dval[CAP];
    __shared__ int didx[CAP];
    __shared__ int hard[NH];

    for (int i = threadIdx.x; i < Dd; i += 256) oq[i] = outq64[(size_t)row * Dd + i];
    __syncthreads();

    int n = ccnt[row]; if (n > CAP) n = CAP;
    for (int c = threadIdx.x; c < n; c += 256) {
        int idx = cand[(size_t)row * CAP + c];
        const float* qr = Qm + (size_t)idx * Dd;
        double dot = 0;
        #pragma unroll 4
        for (int i = 0; i < Dd; ++i) dot += oq[i] * (double)qr[i];
        dval[c] = dot / 0.07;
        didx[c] = idx;
    }
    __syncthreads();

    // exact rank (ties -> lower index first, matching lax.top_k)
    for (int c = threadIdx.x; c < n; c += 256) {
        double v = dval[c]; int id = didx[c];
        int r = 0;
        for (int j = 0; j < n; ++j) {
            double vj = dval[j];
            r += (vj > v) || (vj == v && didx[j] < id);
        }
        if (r < NH) hard[r] = id;
    }
    __syncthreads();

    int t = threadIdx.x;
    if (t < S1n) {
        double a = (double)alpha[(size_t)row * S1n + t];
        int g1 = hard[i1a[(size_t)row * S1n + t]];
        int g2 = hard[i1b[(size_t)row * S1n + t]];
        const float* q1 = Qm + (size_t)g1 * Dd;
        const float* q2 = Qm + (size_t)g2 * Dd;
        double nn = 0, qd = 0;
        #pragma unroll 4
        for (int i = 0; i < Dd; ++i) {
            double m = a * (double)q1[i] + (1.0 - a) * (double)q2[i];
            nn += m * m; qd += oq[i] * m;
        }
        double logit = qd / fmax(sqrt(nn), 1e-12) / 0.07;
        out[(size_t)row * ROWLEN + 1 + Kq + t] = (float)logit;
    } else if (t < S1n + S2n) {
        int s = t - S1n;
        double bb = (double)beta[(size_t)row * S2n + s] * 0.5;
        int g = hard[i2[(size_t)row * S2n + s]];
        const float* qg = Qm + (size_t)g * Dd;
        double nn = 0, qd = 0;
        #pragma unroll 4
        for (int i = 0; i < Dd; ++i) {
            double m = bb * oq[i] + (1.0 - bb) * (double)qg[i];
            nn += m * m; qd += oq[i] * m;
        }
        double logit = qd / fmax(sqrt(nn), 1e-12) / 0.07;
        out[(size_t)row * ROWLEN + 1 + Kq + S1n + s] = (float)logit;
    }
}

extern "C" void kernel_launch(void* const* d_in, const int* in_sizes, int n_in,
                              void* d_out, int out_size, void* d_ws, size_t ws_size,
                              hipStream_t stream) {
    const float* q     = (const float*)d_in[0];
    const float* k     = (const float*)d_in[1];
    const float* Wq    = (const float*)d_in[2];
    const float* Wk    = (const float*)d_in[3];
    const float* queue = (const float*)d_in[4];
    const float* alpha = (const float*)d_in[5];
    const float* beta  = (const float*)d_in[6];
    const int*   i1a   = (const int*)d_in[7];
    const int*   i1b   = (const int*)d_in[8];
    const int*   i2    = (const int*)d_in[9];
    float* out = (float*)d_out;

    // workspace layout (all 8B aligned)
    char* ws = (char*)d_ws;
    double* outq64 = (double*)(ws);                          // 256*128*8   = 262144
    double* part   = (double*)(ws + 262144);                 // 4*512*128*8 = 2097152
    float*  outq32 = (float*)(ws + 262144 + 2097152);        // 256*128*4   = 131072
    int*    cand   = (int*)(ws + 262144 + 2097152 + 131072); // 256*2048*4  = 2097152
    int*    ccnt   = (int*)(ws + 262144 + 2097152 + 131072 + 2097152); // 1024

    moco_a1<<<dim3(NCHUNK, 64), 256, 0, stream>>>(q, k, Wq, Wk, part);
    moco_a2<<<dim3(Bsz), 128, 0, stream>>>(part, outq64, outq32, out);
    moco_gemmB<<<dim3(Kq / BN, Bsz / BM), 256, 0, stream>>>(outq32, queue, out);
    moco_topcand<<<dim3(Bsz), 256, 0, stream>>>(out, cand, ccnt);
    moco_finalize<<<dim3(Bsz), 256, 0, stream>>>(outq64, queue, cand, ccnt,
                                                 alpha, beta, i1a, i1b, i2, out);
}

// Round 2
// 364.245 us; speedup vs baseline: 1.8152x; 1.8152x over previous
//
#include <hip/hip_runtime.h>
#include <hip/hip_bf16.h>
#include <math.h>

// Problem constants
#define Bsz   256
#define INDIM 2048
#define Dd    128
#define Kq    65536
#define NH    32
#define S1n   16
#define S2n   16
#define ROWLEN (1 + Kq + S1n + S2n)   // 65569
#define CAP   2048
#define NCHUNK 8                       // split-K chunks of 256 for encoder GEMM
#define CK    256                      // K per chunk

// ---------------- Kernel A1: fp64 split-K encoder GEMM ----------------
// virtual rows 0..255 = q @ W_q ; 256..511 = k @ (0.999*W_k + (1-0.999)*W_q)
// EMA distributed over the dot: 0.999*(k.Wk) + (1-0.999)*(k.Wq)  (fp64)
// grid: (NCHUNK, 64), block 256. Each block: 8 rows x 128 cols x 256 k-chunk.
// Thread map: dt = tid&31 -> d0 = dt*4 (float4 W loads); rt = tid>>5 -> row.
__global__ __launch_bounds__(256) void moco_a1(const float* __restrict__ q,
                                               const float* __restrict__ k,
                                               const float* __restrict__ Wq,
                                               const float* __restrict__ Wk,
                                               double* __restrict__ part) {
    int kc    = blockIdx.x;        // 0..NCHUNK-1
    int grp   = blockIdx.y;        // 0..63
    int vrow0 = grp * 8;
    bool isK  = (vrow0 >= Bsz);
    const float* inp = isK ? k : q;
    int row0 = isK ? (vrow0 - Bsz) : vrow0;
    int i0 = kc * CK;

    __shared__ float s_in[8 * CK];
    for (int idx = threadIdx.x; idx < 8 * CK; idx += 256) {
        int rr = idx >> 8, ii = idx & (CK - 1);
        s_in[idx] = inp[(size_t)(row0 + rr) * INDIM + i0 + ii];
    }
    __syncthreads();

    int dt = threadIdx.x & 31;
    int rt = threadIdx.x >> 5;
    int d0 = dt * 4;
    const float* baseWq = Wq + (size_t)i0 * Dd + d0;
    const float* baseWk = Wk + (size_t)i0 * Dd + d0;
    const float* srow = &s_in[rt * CK];

    double accA0 = 0, accA1 = 0, accA2 = 0, accA3 = 0;
    double res0, res1, res2, res3;

    if (isK) {
        double accB0 = 0, accB1 = 0, accB2 = 0, accB3 = 0;
        #pragma unroll 4
        for (int i = 0; i < CK; ++i) {
            float4 wk = *(const float4*)(baseWk + (size_t)i * Dd);
            float4 wq = *(const float4*)(baseWq + (size_t)i * Dd);
            double a = (double)srow[i];
            accA0 += a * (double)wk.x; accA1 += a * (double)wk.y;
            accA2 += a * (double)wk.z; accA3 += a * (double)wk.w;
            accB0 += a * (double)wq.x; accB1 += a * (double)wq.y;
            accB2 += a * (double)wq.z; accB3 += a * (double)wq.w;
        }
        const double M = 0.999, OM = 1.0 - 0.999;
        res0 = M * accA0 + OM * accB0;
        res1 = M * accA1 + OM * accB1;
        res2 = M * accA2 + OM * accB2;
        res3 = M * accA3 + OM * accB3;
    } else {
        #pragma unroll 8
        for (int i = 0; i < CK; ++i) {
            float4 wq = *(const float4*)(baseWq + (size_t)i * Dd);
            double a = (double)srow[i];
            accA0 += a * (double)wq.x; accA1 += a * (double)wq.y;
            accA2 += a * (double)wq.z; accA3 += a * (double)wq.w;
        }
        res0 = accA0; res1 = accA1; res2 = accA2; res3 = accA3;
    }
    double* pout = part + (((size_t)kc * 512) + vrow0 + rt) * Dd + d0;
    pout[0] = res0; pout[1] = res1; pout[2] = res2; pout[3] = res3;
}

// ---------------- Kernel A2: combine chunks, normalize (f64), pos logit, labels ----
// grid: 256 (one per b), block 128 (one per d)
__global__ __launch_bounds__(128) void moco_a2(const double* __restrict__ part,
                                               double* __restrict__ outq64,
                                               float* __restrict__ outq32,
                                               float* __restrict__ out) {
    int b = blockIdx.x, d = threadIdx.x;
    double sq = 0, sk = 0;
    #pragma unroll
    for (int kc = 0; kc < NCHUNK; ++kc) {
        sq += part[(((size_t)kc * 512) + b) * Dd + d];
        sk += part[(((size_t)kc * 512) + Bsz + b) * Dd + d];
    }
    __shared__ double red[128];
    red[d] = sq * sq; __syncthreads();
    for (int s = 64; s > 0; s >>= 1) { if (d < s) red[d] += red[d + s]; __syncthreads(); }
    double nq = sqrt(red[0]); __syncthreads();
    red[d] = sk * sk; __syncthreads();
    for (int s = 64; s > 0; s >>= 1) { if (d < s) red[d] += red[d + s]; __syncthreads(); }
    double nk = sqrt(red[0]); __syncthreads();

    double oq = sq / fmax(nq, 1e-12);
    double ok = sk / fmax(nk, 1e-12);
    outq64[(size_t)b * Dd + d] = oq;
    outq32[(size_t)b * Dd + d] = (float)oq;

    red[d] = oq * ok; __syncthreads();
    for (int s = 64; s > 0; s >>= 1) { if (d < s) red[d] += red[d + s]; __syncthreads(); }
    if (d == 0) {
        out[(size_t)b * ROWLEN] = (float)(red[0] / 0.07);
        ((int*)out)[(size_t)Bsz * ROWLEN + b] = 0;   // labels
    }
}

// ---------------- Kernel B: fp32 GEMM out_q @ queue^T / T -> out[:,1:1+K] ----------
// 256 threads as 16(tx: n, 4 consecutive) x 16(ty: m, 8 consecutive);
// all LDS fragment reads are ds_read_b128.
#define BM 128
#define BN 64
#define BK 64
__global__ __launch_bounds__(256) void moco_gemmB(const float* __restrict__ A,
                                                  const float* __restrict__ Q,
                                                  float* __restrict__ out) {
    int bn0 = blockIdx.x * BN;
    int bm0 = blockIdx.y * BM;
    __shared__ float a_s[BK][BM + 4];
    __shared__ float b_s[BK][BN + 4];
    int tx = threadIdx.x & 15;   // n group
    int ty = threadIdx.x >> 4;   // m group
    int m0 = ty * 8, n0 = tx * 4;
    float acc[8][4] = {};

    for (int k0 = 0; k0 < Dd; k0 += BK) {
        for (int idx = threadIdx.x; idx < BM * BK; idx += 256) {
            int kk = idx & (BK - 1), m = idx >> 6;
            a_s[kk][m] = A[(size_t)(bm0 + m) * Dd + k0 + kk];
        }
        for (int idx = threadIdx.x; idx < BN * BK; idx += 256) {
            int kk = idx & (BK - 1), n = idx >> 6;
            b_s[kk][n] = Q[(size_t)(bn0 + n) * Dd + k0 + kk];
        }
        __syncthreads();
        #pragma unroll 8
        for (int kk = 0; kk < BK; ++kk) {
            float4 a0 = *(const float4*)&a_s[kk][m0];
            float4 a1 = *(const float4*)&a_s[kk][m0 + 4];
            float4 b0 = *(const float4*)&b_s[kk][n0];
            float ar[8] = {a0.x, a0.y, a0.z, a0.w, a1.x, a1.y, a1.z, a1.w};
            float br[4] = {b0.x, b0.y, b0.z, b0.w};
            #pragma unroll
            for (int i = 0; i < 8; ++i)
                #pragma unroll
                for (int j = 0; j < 4; ++j)
                    acc[i][j] += ar[i] * br[j];
        }
        __syncthreads();
    }
    const float invT = (float)(1.0 / 0.07);
    #pragma unroll
    for (int i = 0; i < 8; ++i) {
        size_t base = (size_t)(bm0 + m0 + i) * ROWLEN + 1 + bn0 + n0;
        #pragma unroll
        for (int j = 0; j < 4; ++j)
            out[base + j] = acc[i][j] * invT;
    }
}

// ---------------- Kernel C: per-row top-candidate selection (histogram) ----------
__global__ __launch_bounds__(512) void moco_topcand(const float* __restrict__ out,
                                                    int* __restrict__ cand,
                                                    int* __restrict__ ccnt) {
    int row = blockIdx.x;
    const float* p = out + (size_t)row * ROWLEN + 1;
    __shared__ unsigned hist[4096];
    __shared__ unsigned tsum[256];
    __shared__ int s_bstar;
    __shared__ int s_cnt;
    for (int i = threadIdx.x; i < 4096; i += 512) hist[i] = 0;
    if (threadIdx.x == 0) s_cnt = 0;
    __syncthreads();

    for (int c = threadIdx.x; c < Kq; c += 512) {
        unsigned u = __float_as_uint(p[c]);
        u = (u & 0x80000000u) ? ~u : (u | 0x80000000u);
        atomicAdd(&hist[u >> 20], 1u);
    }
    __syncthreads();
    // parallel-ish threshold: 256 groups of 16 bins
    if (threadIdx.x < 256) {
        unsigned s = 0;
        #pragma unroll
        for (int b = 0; b < 16; ++b) s += hist[threadIdx.x * 16 + b];
        tsum[threadIdx.x] = s;
    }
    __syncthreads();
    if (threadIdx.x == 0) {
        unsigned cum = 0;
        int g = 255;
        for (; g > 0; --g) { if (cum + tsum[g] >= NH) break; cum += tsum[g]; }
        // find exact bin within group g (scanning from top)
        int bin = g * 16 + 15;
        for (; bin > g * 16; --bin) { cum += hist[bin]; if (cum >= NH) break; }
        if (bin == g * 16) cum += hist[bin];
        s_bstar = (bin > 0) ? (bin - 1) : 0;   // one extra bin of safety margin
    }
    __syncthreads();
    unsigned bstar = (unsigned)s_bstar;
    for (int c = threadIdx.x; c < Kq; c += 512) {
        unsigned u = __float_as_uint(p[c]);
        u = (u & 0x80000000u) ? ~u : (u | 0x80000000u);
        if ((u >> 20) >= bstar) {
            int pos = atomicAdd(&s_cnt, 1);
            if (pos < CAP) cand[(size_t)row * CAP + pos] = c;
        }
    }
    __syncthreads();
    if (threadIdx.x == 0) ccnt[row] = (s_cnt < CAP) ? s_cnt : CAP;
}

// ---------------- Kernel D: fp64 re-rank + mixed-negative logits ----------------
__global__ __launch_bounds__(256) void moco_finalize(const double* __restrict__ outq64,
                                                     const float* __restrict__ Qm,
                                                     const int* __restrict__ cand,
                                                     const int* __restrict__ ccnt,
                                                     const float* __restrict__ alpha,
                                                     const float* __restrict__ beta,
                                                     const int* __restrict__ i1a,
                                                     const int* __restrict__ i1b,
                                                     const int* __restrict__ i2,
                                                     float* __restrict__ out) {
    int row = blockIdx.x;
    __shared__ double oq[Dd];
    __shared__ double dval[CAP];
    __shared__ int didx[CAP];
    __shared__ int hard[NH];

    for (int i = threadIdx.x; i < Dd; i += 256) oq[i] = outq64[(size_t)row * Dd + i];
    __syncthreads();

    int n = ccnt[row]; if (n > CAP) n = CAP;
    for (int c = threadIdx.x; c < n; c += 256) {
        int idx = cand[(size_t)row * CAP + c];
        const float* qr = Qm + (size_t)idx * Dd;
        double dot = 0;
        #pragma unroll 4
        for (int i = 0; i < Dd; ++i) dot += oq[i] * (double)qr[i];
        dval[c] = dot / 0.07;
        didx[c] = idx;
    }
    __syncthreads();

    // exact rank (ties -> lower index first, matching lax.top_k)
    for (int c = threadIdx.x; c < n; c += 256) {
        double v = dval[c]; int id = didx[c];
        int r = 0;
        for (int j = 0; j < n; ++j) {
            double vj = dval[j];
            r += (vj > v) || (vj == v && didx[j] < id);
        }
        if (r < NH) hard[r] = id;
    }
    __syncthreads();

    int t = threadIdx.x;
    if (t < S1n) {
        double a = (double)alpha[(size_t)row * S1n + t];
        int g1 = hard[i1a[(size_t)row * S1n + t]];
        int g2 = hard[i1b[(size_t)row * S1n + t]];
        const float* q1 = Qm + (size_t)g1 * Dd;
        const float* q2 = Qm + (size_t)g2 * Dd;
        double nn = 0, qd = 0;
        #pragma unroll 4
        for (int i = 0; i < Dd; ++i) {
            double m = a * (double)q1[i] + (1.0 - a) * (double)q2[i];
            nn += m * m; qd += oq[i] * m;
        }
        double logit = qd / fmax(sqrt(nn), 1e-12) / 0.07;
        out[(size_t)row * ROWLEN + 1 + Kq + t] = (float)logit;
    } else if (t < S1n + S2n) {
        int s = t - S1n;
        double bb = (double)beta[(size_t)row * S2n + s] * 0.5;
        int g = hard[i2[(size_t)row * S2n + s]];
        const float* qg = Qm + (size_t)g * Dd;
        double nn = 0, qd = 0;
        #pragma unroll 4
        for (int i = 0; i < Dd; ++i) {
            double m = bb * oq[i] + (1.0 - bb) * (double)qg[i];
            nn += m * m; qd += oq[i] * m;
        }
        double logit = qd / fmax(sqrt(nn), 1e-12) / 0.07;
        out[(size_t)row * ROWLEN + 1 + Kq + S1n + s] = (float)logit;
    }
}

extern "C" void kernel_launch(void* const* d_in, const int* in_sizes, int n_in,
                              void* d_out, int out_size, void* d_ws, size_t ws_size,
                              hipStream_t stream) {
    const float* q     = (const float*)d_in[0];
    const float* k     = (const float*)d_in[1];
    const float* Wq    = (const float*)d_in[2];
    const float* Wk    = (const float*)d_in[3];
    const float* queue = (const float*)d_in[4];
    const float* alpha = (const float*)d_in[5];
    const float* beta  = (const float*)d_in[6];
    const int*   i1a   = (const int*)d_in[7];
    const int*   i1b   = (const int*)d_in[8];
    const int*   i2    = (const int*)d_in[9];
    float* out = (float*)d_out;

    // workspace layout: part (4 MB) is dead after a2; cand (2 MB) aliases it
    // (kernels are stream-ordered, so no overlap in lifetime).
    char* ws = (char*)d_ws;
    double* part   = (double*)(ws);                      // 8*512*128*8 = 4,194,304
    int*    cand   = (int*)(ws);                         // 256*2048*4  = 2,097,152 (alias)
    double* outq64 = (double*)(ws + 4194304);            // 262,144
    float*  outq32 = (float*)(ws + 4194304 + 262144);    // 131,072
    int*    ccnt   = (int*)(ws + 4194304 + 262144 + 131072); // 1,024

    moco_a1<<<dim3(NCHUNK, 64), 256, 0, stream>>>(q, k, Wq, Wk, part);
    moco_a2<<<dim3(Bsz), 128, 0, stream>>>(part, outq64, outq32, out);
    moco_gemmB<<<dim3(Kq / BN, Bsz / BM), 256, 0, stream>>>(outq32, queue, out);
    moco_topcand<<<dim3(Bsz), 512, 0, stream>>>(out, cand, ccnt);
    moco_finalize<<<dim3(Bsz), 256, 0, stream>>>(outq64, queue, cand, ccnt,
                                                 alpha, beta, i1a, i1b, i2, out);
}

// Round 3
// 293.231 us; speedup vs baseline: 2.2548x; 1.2422x over previous
//
#include <hip/hip_runtime.h>
#include <hip/hip_bf16.h>
#include <math.h>

// Problem constants
#define Bsz   256
#define INDIM 2048
#define Dd    128
#define Kq    65536
#define NH    32
#define S1n   16
#define S2n   16
#define ROWLEN (1 + Kq + S1n + S2n)   // 65569
#define CAP   2048
#define NCHUNK 8                       // split-K chunks of 256 for encoder GEMM
#define CK    256                      // K per chunk

typedef __attribute__((ext_vector_type(8))) short short8;
typedef __attribute__((ext_vector_type(4))) float f32x4;
union U16x8 { uint4 u4; short8 s8; };

static __device__ inline unsigned short bf16rne(float f) {
    unsigned u = __float_as_uint(f);
    unsigned r = (u + 0x7FFFu + ((u >> 16) & 1u)) >> 16;
    return (unsigned short)r;
}

// ---------------- Kernel A1: fp64 split-K encoder GEMM ----------------
__global__ __launch_bounds__(256) void moco_a1(const float* __restrict__ q,
                                               const float* __restrict__ k,
                                               const float* __restrict__ Wq,
                                               const float* __restrict__ Wk,
                                               double* __restrict__ part) {
    int kc    = blockIdx.x;        // 0..NCHUNK-1
    int grp   = blockIdx.y;        // 0..63
    int vrow0 = grp * 8;
    bool isK  = (vrow0 >= Bsz);
    const float* inp = isK ? k : q;
    int row0 = isK ? (vrow0 - Bsz) : vrow0;
    int i0 = kc * CK;

    __shared__ float s_in[8 * CK];
    for (int idx = threadIdx.x; idx < 8 * CK; idx += 256) {
        int rr = idx >> 8, ii = idx & (CK - 1);
        s_in[idx] = inp[(size_t)(row0 + rr) * INDIM + i0 + ii];
    }
    __syncthreads();

    int dt = threadIdx.x & 31;
    int rt = threadIdx.x >> 5;
    int d0 = dt * 4;
    const float* baseWq = Wq + (size_t)i0 * Dd + d0;
    const float* baseWk = Wk + (size_t)i0 * Dd + d0;
    const float* srow = &s_in[rt * CK];

    double accA0 = 0, accA1 = 0, accA2 = 0, accA3 = 0;
    double res0, res1, res2, res3;

    if (isK) {
        double accB0 = 0, accB1 = 0, accB2 = 0, accB3 = 0;
        #pragma unroll 4
        for (int i = 0; i < CK; ++i) {
            float4 wk = *(const float4*)(baseWk + (size_t)i * Dd);
            float4 wq = *(const float4*)(baseWq + (size_t)i * Dd);
            double a = (double)srow[i];
            accA0 += a * (double)wk.x; accA1 += a * (double)wk.y;
            accA2 += a * (double)wk.z; accA3 += a * (double)wk.w;
            accB0 += a * (double)wq.x; accB1 += a * (double)wq.y;
            accB2 += a * (double)wq.z; accB3 += a * (double)wq.w;
        }
        const double M = 0.999, OM = 1.0 - 0.999;
        res0 = M * accA0 + OM * accB0;
        res1 = M * accA1 + OM * accB1;
        res2 = M * accA2 + OM * accB2;
        res3 = M * accA3 + OM * accB3;
    } else {
        #pragma unroll 8
        for (int i = 0; i < CK; ++i) {
            float4 wq = *(const float4*)(baseWq + (size_t)i * Dd);
            double a = (double)srow[i];
            accA0 += a * (double)wq.x; accA1 += a * (double)wq.y;
            accA2 += a * (double)wq.z; accA3 += a * (double)wq.w;
        }
        res0 = accA0; res1 = accA1; res2 = accA2; res3 = accA3;
    }
    double* pout = part + (((size_t)kc * 512) + vrow0 + rt) * Dd + d0;
    pout[0] = res0; pout[1] = res1; pout[2] = res2; pout[3] = res3;
}

// ---------------- Kernel A2: combine, normalize (f64), pos logit, labels, bf16 out_q ----
__global__ __launch_bounds__(128) void moco_a2(const double* __restrict__ part,
                                               double* __restrict__ outq64,
                                               unsigned short* __restrict__ outq16,
                                               float* __restrict__ out) {
    int b = blockIdx.x, d = threadIdx.x;
    double sq = 0, sk = 0;
    #pragma unroll
    for (int kc = 0; kc < NCHUNK; ++kc) {
        sq += part[(((size_t)kc * 512) + b) * Dd + d];
        sk += part[(((size_t)kc * 512) + Bsz + b) * Dd + d];
    }
    __shared__ double red[128];
    red[d] = sq * sq; __syncthreads();
    for (int s = 64; s > 0; s >>= 1) { if (d < s) red[d] += red[d + s]; __syncthreads(); }
    double nq = sqrt(red[0]); __syncthreads();
    red[d] = sk * sk; __syncthreads();
    for (int s = 64; s > 0; s >>= 1) { if (d < s) red[d] += red[d + s]; __syncthreads(); }
    double nk = sqrt(red[0]); __syncthreads();

    double oq = sq / fmax(nq, 1e-12);
    double ok = sk / fmax(nk, 1e-12);
    outq64[(size_t)b * Dd + d] = oq;
    outq16[(size_t)b * Dd + d] = bf16rne((float)oq);

    red[d] = oq * ok; __syncthreads();
    for (int s = 64; s > 0; s >>= 1) { if (d < s) red[d] += red[d + s]; __syncthreads(); }
    if (d == 0) {
        out[(size_t)b * ROWLEN] = (float)(red[0] / 0.07);
        ((int*)out)[(size_t)Bsz * ROWLEN + b] = 0;   // labels
    }
}

// ---------------- Kernel B: bf16 MFMA GEMM out_q @ queue^T / T -> out[:,1:1+K] -------
// grid 1024 blocks (N), 256 threads = 4 waves; BM=256 (wave w: rows w*64..+63), BN=64.
// A frags straight from global bf16 (L2-hot 64 KB); Q tile fp32->bf16 into LDS.
#define GB_BN 64
__global__ __launch_bounds__(256) void moco_gemmB(const unsigned short* __restrict__ outq16,
                                                  const float* __restrict__ Q,
                                                  float* __restrict__ out) {
    int bn0 = blockIdx.x * GB_BN;
    int tid = threadIdx.x;
    int w = tid >> 6, lane = tid & 63;
    int quad = lane >> 4, l16 = lane & 15;

    __shared__ unsigned short q_lds[64 * 136];   // stride 136 bf16 (272 B, 16B-aligned rows)

    // stage Q tile: 64 rows x 128 k, convert fp32->bf16 (RNE)
    #pragma unroll
    for (int it = 0; it < 4; ++it) {
        int chunk = tid + it * 256;          // 0..1023
        int row = chunk >> 4, kb = chunk & 15;
        const float4* g = (const float4*)(Q + (size_t)(bn0 + row) * Dd + kb * 8);
        float4 f0 = g[0], f1 = g[1];
        uint4 pk;
        pk.x = ((unsigned)bf16rne(f0.y) << 16) | bf16rne(f0.x);
        pk.y = ((unsigned)bf16rne(f0.w) << 16) | bf16rne(f0.z);
        pk.z = ((unsigned)bf16rne(f1.y) << 16) | bf16rne(f1.x);
        pk.w = ((unsigned)bf16rne(f1.w) << 16) | bf16rne(f1.z);
        *(uint4*)&q_lds[row * 136 + kb * 8] = pk;
    }

    // A fragments: afr[i][kc] = A[w*64+i*16+l16][kc*32+quad*8 .. +7]
    short8 afr[4][4];
    #pragma unroll
    for (int i = 0; i < 4; ++i)
        #pragma unroll
        for (int kc = 0; kc < 4; ++kc) {
            U16x8 u;
            u.u4 = *(const uint4*)(outq16 + (size_t)(w * 64 + i * 16 + l16) * Dd + kc * 32 + quad * 8);
            afr[i][kc] = u.s8;
        }
    __syncthreads();

    f32x4 acc[4][4];
    #pragma unroll
    for (int i = 0; i < 4; ++i)
        #pragma unroll
        for (int j = 0; j < 4; ++j)
            acc[i][j] = (f32x4){0.f, 0.f, 0.f, 0.f};

    #pragma unroll
    for (int kc = 0; kc < 4; ++kc) {
        short8 bfr[4];
        #pragma unroll
        for (int j = 0; j < 4; ++j)
            bfr[j] = *(const short8*)&q_lds[(j * 16 + l16) * 136 + kc * 32 + quad * 8];
        #pragma unroll
        for (int i = 0; i < 4; ++i)
            #pragma unroll
            for (int j = 0; j < 4; ++j)
                acc[i][j] = __builtin_amdgcn_mfma_f32_16x16x32_bf16(afr[i][kc], bfr[j], acc[i][j], 0, 0, 0);
    }

    const float invT = (float)(1.0 / 0.07);
    #pragma unroll
    for (int i = 0; i < 4; ++i) {
        int rbase = w * 64 + i * 16 + quad * 4;
        #pragma unroll
        for (int reg = 0; reg < 4; ++reg) {
            size_t ro = (size_t)(rbase + reg) * ROWLEN + 1 + bn0;
            #pragma unroll
            for (int j = 0; j < 4; ++j)
                out[ro + j * 16 + l16] = acc[i][j][reg] * invT;
        }
    }
}

// ---------------- Kernel C: per-row top-candidate selection (histogram) ----------
__global__ __launch_bounds__(512) void moco_topcand(const float* __restrict__ out,
                                                    int* __restrict__ cand,
                                                    int* __restrict__ ccnt) {
    int row = blockIdx.x;
    const float* p = out + (size_t)row * ROWLEN + 1;
    __shared__ unsigned hist[4096];
    __shared__ unsigned tsum[256];
    __shared__ unsigned ssum[16];
    __shared__ int s_bstar;
    __shared__ int s_cnt;
    for (int i = threadIdx.x; i < 4096; i += 512) hist[i] = 0;
    if (threadIdx.x == 0) s_cnt = 0;
    __syncthreads();

    #pragma unroll 4
    for (int c = threadIdx.x; c < Kq; c += 512) {
        unsigned u = __float_as_uint(p[c]);
        u = (u & 0x80000000u) ? ~u : (u | 0x80000000u);
        atomicAdd(&hist[u >> 20], 1u);
    }
    __syncthreads();
    if (threadIdx.x < 256) {
        unsigned s = 0;
        #pragma unroll
        for (int b = 0; b < 16; ++b) s += hist[threadIdx.x * 16 + b];
        tsum[threadIdx.x] = s;
    }
    __syncthreads();
    if (threadIdx.x < 16) {
        unsigned s = 0;
        #pragma unroll
        for (int g = 0; g < 16; ++g) s += tsum[threadIdx.x * 16 + g];
        ssum[threadIdx.x] = s;
    }
    __syncthreads();
    if (threadIdx.x == 0) {
        unsigned cum = 0;
        int sg = 15;
        for (; sg > 0; --sg) { if (cum + ssum[sg] >= NH) break; cum += ssum[sg]; }
        int g = sg * 16 + 15;
        for (; g > sg * 16; --g) { if (cum + tsum[g] >= NH) break; cum += tsum[g]; }
        int bin = g * 16 + 15;
        for (; bin > g * 16; --bin) { cum += hist[bin]; if (cum >= NH) break; }
        s_bstar = (bin > 0) ? (bin - 1) : 0;   // one extra bin of safety margin
    }
    __syncthreads();
    unsigned bstar = (unsigned)s_bstar;
    #pragma unroll 4
    for (int c = threadIdx.x; c < Kq; c += 512) {
        unsigned u = __float_as_uint(p[c]);
        u = (u & 0x80000000u) ? ~u : (u | 0x80000000u);
        if ((u >> 20) >= bstar) {
            int pos = atomicAdd(&s_cnt, 1);
            if (pos < CAP) cand[(size_t)row * CAP + pos] = c;
        }
    }
    __syncthreads();
    if (threadIdx.x == 0) ccnt[row] = (s_cnt < CAP) ? s_cnt : CAP;
}

// ---------------- Kernel D: fp64 re-rank + mixed-negative logits ----------------
__global__ __launch_bounds__(256) void moco_finalize(const double* __restrict__ outq64,
                                                     const float* __restrict__ Qm,
                                                     const int* __restrict__ cand,
                                                     const int* __restrict__ ccnt,
                                                     const float* __restrict__ alpha,
                                                     const float* __restrict__ beta,
                                                     const int* __restrict__ i1a,
                                                     const int* __restrict__ i1b,
                                                     const int* __restrict__ i2,
                                                     float* __restrict__ out) {
    int row = blockIdx.x;
    __shared__ double oq[Dd];
    __shared__ double dval[CAP];
    __shared__ int didx[CAP];
    __shared__ int hard[NH];

    for (int i = threadIdx.x; i < Dd; i += 256) oq[i] = outq64[(size_t)row * Dd + i];
    __syncthreads();

    int n = ccnt[row]; if (n > CAP) n = CAP;
    for (int c = threadIdx.x; c < n; c += 256) {
        int idx = cand[(size_t)row * CAP + c];
        const float* qr = Qm + (size_t)idx * Dd;
        double dot = 0;
        #pragma unroll 4
        for (int i = 0; i < Dd; ++i) dot += oq[i] * (double)qr[i];
        dval[c] = dot / 0.07;
        didx[c] = idx;
    }
    __syncthreads();

    // exact rank (ties -> lower index first, matching lax.top_k)
    for (int c = threadIdx.x; c < n; c += 256) {
        double v = dval[c]; int id = didx[c];
        int r = 0;
        for (int j = 0; j < n; ++j) {
            double vj = dval[j];
            r += (vj > v) || (vj == v && didx[j] < id);
        }
        if (r < NH) hard[r] = id;
    }
    __syncthreads();

    int t = threadIdx.x;
    if (t < S1n) {
        double a = (double)alpha[(size_t)row * S1n + t];
        int g1 = hard[i1a[(size_t)row * S1n + t]];
        int g2 = hard[i1b[(size_t)row * S1n + t]];
        const float* q1 = Qm + (size_t)g1 * Dd;
        const float* q2 = Qm + (size_t)g2 * Dd;
        double nn = 0, qd = 0;
        #pragma unroll 4
        for (int i = 0; i < Dd; ++i) {
            double m = a * (double)q1[i] + (1.0 - a) * (double)q2[i];
            nn += m * m; qd += oq[i] * m;
        }
        double logit = qd / fmax(sqrt(nn), 1e-12) / 0.07;
        out[(size_t)row * ROWLEN + 1 + Kq + t] = (float)logit;
    } else if (t < S1n + S2n) {
        int s = t - S1n;
        double bb = (double)beta[(size_t)row * S2n + s] * 0.5;
        int g = hard[i2[(size_t)row * S2n + s]];
        const float* qg = Qm + (size_t)g * Dd;
        double nn = 0, qd = 0;
        #pragma unroll 4
        for (int i = 0; i < Dd; ++i) {
            double m = bb * oq[i] + (1.0 - bb) * (double)qg[i];
            nn += m * m; qd += oq[i] * m;
        }
        double logit = qd / fmax(sqrt(nn), 1e-12) / 0.07;
        out[(size_t)row * ROWLEN + 1 + Kq + S1n + s] = (float)logit;
    }
}

extern "C" void kernel_launch(void* const* d_in, const int* in_sizes, int n_in,
                              void* d_out, int out_size, void* d_ws, size_t ws_size,
                              hipStream_t stream) {
    const float* q     = (const float*)d_in[0];
    const float* k     = (const float*)d_in[1];
    const float* Wq    = (const float*)d_in[2];
    const float* Wk    = (const float*)d_in[3];
    const float* queue = (const float*)d_in[4];
    const float* alpha = (const float*)d_in[5];
    const float* beta  = (const float*)d_in[6];
    const int*   i1a   = (const int*)d_in[7];
    const int*   i1b   = (const int*)d_in[8];
    const int*   i2    = (const int*)d_in[9];
    float* out = (float*)d_out;

    // workspace: part (4 MB, dead after a2) aliases cand (2 MB, born in topcand)
    char* ws = (char*)d_ws;
    double* part   = (double*)(ws);                        // 8*512*128*8 = 4,194,304
    int*    cand   = (int*)(ws);                           // 256*2048*4  = 2,097,152 (alias)
    double* outq64 = (double*)(ws + 4194304);              // 262,144
    unsigned short* outq16 = (unsigned short*)(ws + 4194304 + 262144); // 65,536
    int*    ccnt   = (int*)(ws + 4194304 + 262144 + 65536); // 1,024

    moco_a1<<<dim3(NCHUNK, 64), 256, 0, stream>>>(q, k, Wq, Wk, part);
    moco_a2<<<dim3(Bsz), 128, 0, stream>>>(part, outq64, outq16, out);
    moco_gemmB<<<dim3(Kq / GB_BN), 256, 0, stream>>>(outq16, queue, out);
    moco_topcand<<<dim3(Bsz), 512, 0, stream>>>(out, cand, ccnt);
    moco_finalize<<<dim3(Bsz), 256, 0, stream>>>(outq64, queue, cand, ccnt,
                                                 alpha, beta, i1a, i1b, i2, out);
}